// Round 1
// baseline (2304.570 us; speedup 1.0000x reference)
//
#include <hip/hip_runtime.h>
#include <math.h>

typedef unsigned short u16;
typedef unsigned int   u32;
typedef __attribute__((ext_vector_type(8))) short bf16x8;
typedef __attribute__((ext_vector_type(4))) float f32x4;

typedef const void __attribute__((address_space(1))) gv1_t;
typedef void       __attribute__((address_space(3))) lv3_t;
#define GLL(g, l) __builtin_amdgcn_global_load_lds((gv1_t*)(g), (lv3_t*)(l), 16, 0, 0)

__device__ __forceinline__ u16 f2b(float x) {
    union { float f; u32 u; } v; v.f = x;
    u32 r = v.u + 0x7FFFu + ((v.u >> 16) & 1u);
    return (u16)(r >> 16);
}
__device__ __forceinline__ float b2f(u32 x) {
    union { u32 u; float f; } v; v.u = x << 16;
    return v.f;
}

// ---------------------------------------------------------------------------
// prep: f32 -> bf16 convert (adj)
// ---------------------------------------------------------------------------
__global__ void cvt_f32_bf16(const float* __restrict__ a, u16* __restrict__ o, int n) {
    for (int i = (blockIdx.x * 256 + threadIdx.x) * 4; i < n; i += gridDim.x * 256 * 4) {
        float4 v = *(const float4*)&a[i];
        uint2 pk;
        pk.x = (u32)f2b(v.x) | ((u32)f2b(v.y) << 16);
        pk.y = (u32)f2b(v.z) | ((u32)f2b(v.w) << 16);
        *(uint2*)&o[i] = pk;
    }
}

// ---------------------------------------------------------------------------
// prep: x = data + temb + semb; write Xn [b][t][n][c] bf16 and XT [(b,c)][t*1024+n] bf16
// grid (16 ntiles, 12 t, 32 b), block 256
// ---------------------------------------------------------------------------
__global__ void prep_x(const float* __restrict__ data, const float* __restrict__ temb,
                       const float* __restrict__ semb, u16* __restrict__ Xn, u16* __restrict__ XT) {
    const int n0 = blockIdx.x * 64, t = blockIdx.y, b = blockIdx.z;
    const int tid = threadIdx.x;
    __shared__ u16 lt[64][66];
#pragma unroll
    for (int p = 0; p < 4; p++) {
        int n = p * 16 + (tid >> 4);
        int c = (tid & 15) * 4;
        size_t gi = ((size_t)(b * 12 + t) * 1024 + n0 + n) * 64 + c;
        float4 v  = *(const float4*)&data[gi];
        float4 tv = *(const float4*)&temb[t * 64 + c];
        float4 sv = *(const float4*)&semb[(n0 + n) * 64 + c];
        u16 u0 = f2b(v.x + tv.x + sv.x);
        u16 u1 = f2b(v.y + tv.y + sv.y);
        u16 u2 = f2b(v.z + tv.z + sv.z);
        u16 u3 = f2b(v.w + tv.w + sv.w);
        uint2 pk; pk.x = (u32)u0 | ((u32)u1 << 16); pk.y = (u32)u2 | ((u32)u3 << 16);
        *(uint2*)&Xn[gi] = pk;
        lt[n][c + 0] = u0; lt[n][c + 1] = u1; lt[n][c + 2] = u2; lt[n][c + 3] = u3;
    }
    __syncthreads();
    const int c = tid >> 2, q = tid & 3;
    u16 u[16];
#pragma unroll
    for (int i = 0; i < 16; i++) u[i] = lt[q * 16 + i][c];
    size_t xo = ((size_t)(b * 64 + c)) * 12288 + (size_t)t * 1024 + n0 + q * 16;
    uint4 p0, p1;
    p0.x = (u32)u[0] | ((u32)u[1] << 16);  p0.y = (u32)u[2] | ((u32)u[3] << 16);
    p0.z = (u32)u[4] | ((u32)u[5] << 16);  p0.w = (u32)u[6] | ((u32)u[7] << 16);
    p1.x = (u32)u[8] | ((u32)u[9] << 16);  p1.y = (u32)u[10] | ((u32)u[11] << 16);
    p1.z = (u32)u[12] | ((u32)u[13] << 16); p1.w = (u32)u[14] | ((u32)u[15] << 16);
    *(uint4*)&XT[xo] = p0;
    *(uint4*)&XT[xo + 8] = p1;
}

// ---------------------------------------------------------------------------
// prep: fc_w [27][64][128] -> Wt [27][128][64] bf16 ; conv weights -> Wc [128][128] bf16
// grid 28 blocks
// ---------------------------------------------------------------------------
__global__ void prep_w(const float* __restrict__ fcw, const float* __restrict__ cwl,
                       const float* __restrict__ cwr, u16* __restrict__ Wt, u16* __restrict__ Wc) {
    const int blk = blockIdx.x, tid = threadIdx.x;
    if (blk < 27) {
        const float* src = fcw + (size_t)blk * 64 * 128;
        u16* dst = Wt + (size_t)blk * 128 * 64;
        for (int e = tid; e < 8192; e += 256) {
            int c = e >> 7, f = e & 127;
            dst[f * 64 + c] = f2b(src[c * 128 + f]);
        }
    } else {
        for (int e = tid; e < 16384; e += 256) {
            int o = e >> 7, k = e & 127;
            float v = (o < 64) ? cwl[(o * 64 + (k & 63)) * 2 + (k >> 6)]
                               : cwr[((o - 64) * 64 + (k & 63)) * 2 + (k >> 6)];
            Wc[o * 128 + k] = f2b(v);
        }
    }
}

// ---------------------------------------------------------------------------
// gated dilated conv as GEMM: out[b,t,n,f] = sigmoid(gl)*tanh(gr)
// A = Xcat [(b,t,n)][128] from Xn, B^T = Wc [128][128]. grid (8,9,32), block 256
// ---------------------------------------------------------------------------
__global__ __launch_bounds__(256) void dconv_gemm(
    const u16* __restrict__ Xn, const u16* __restrict__ Wc,
    const float* __restrict__ cbl, const float* __restrict__ cbr,
    float* __restrict__ out) {
    const int n0 = blockIdx.x * 128, t = blockIdx.y, b = blockIdx.z;
    const int tid = threadIdx.x, lane = tid & 63, wid = tid >> 6;
    __shared__ u16 alds[2][128 * 32];
    const u16* base0 = Xn + (size_t)(b * 12 + t) * 1024 * 64;
    const u16* base3 = Xn + (size_t)(b * 12 + t + 3) * 1024 * 64;

    auto stage = [&](int buf, int kt) {
        int k0 = kt * 32;
#pragma unroll
        for (int q = 0; q < 2; q++) {
            int r = wid * 32 + q * 16 + (lane >> 2);
            int k = k0 + (lane & 3) * 8;
            const u16* gs = (k < 64) ? base0 + (size_t)(n0 + r) * 64 + k
                                     : base3 + (size_t)(n0 + r) * 64 + (k - 64);
            GLL(gs, &alds[buf][(wid * 32 + q * 16) * 32]);
        }
    };

    f32x4 acc[2][8] = {};
    stage(0, 0);
    __syncthreads();
    const int a_off = (wid * 32 + (lane & 15)) * 32 + (lane >> 4) * 8;
    for (int kt = 0; kt < 4; kt++) {
        int cur = kt & 1;
        if (kt < 3) stage(cur ^ 1, kt + 1);
        bf16x8 af[2];
#pragma unroll
        for (int m = 0; m < 2; m++) af[m] = *(const bf16x8*)&alds[cur][a_off + m * 16 * 32];
#pragma unroll
        for (int n = 0; n < 8; n++) {
            bf16x8 bq = *(const bf16x8*)&Wc[(n * 16 + (lane & 15)) * 128 + kt * 32 + (lane >> 4) * 8];
#pragma unroll
            for (int m = 0; m < 2; m++)
                acc[m][n] = __builtin_amdgcn_mfma_f32_16x16x32_bf16(af[m], bq, acc[m][n], 0, 0, 0);
        }
        __syncthreads();
    }
#pragma unroll
    for (int m = 0; m < 2; m++) {
#pragma unroll
        for (int n = 0; n < 4; n++) {
            int fp = n * 16 + (lane & 15);
            float b1 = cbl[fp], b2 = cbr[fp];
#pragma unroll
            for (int j = 0; j < 4; j++) {
                int row = wid * 32 + m * 16 + (lane >> 4) * 4 + j;
                float gl = acc[m][n][j] + b1;
                float gr = acc[m][n + 4][j] + b2;
                out[((size_t)(b * 9 + t) * 1024 + n0 + row) * 64 + fp] =
                    (1.0f / (1.0f + expf(-gl))) * tanhf(gr);
            }
        }
    }
}

// ---------------------------------------------------------------------------
// main aggregation GEMM: Y[(b,c)][v] = sum_w P[(b,c)][w] * adj[v][w]
// STAGE 0: A rows from XT with window offset; STAGE 1: A = P [z][2048][4096]
// grid (Nout/128, 16, nwin), block 256 (4 waves, 2x2 of 64x64)
// ---------------------------------------------------------------------------
template <int STAGE>
__global__ __launch_bounds__(256) void agg_gemm(
    const u16* __restrict__ A, const u16* __restrict__ Bt,
    u16* __restrict__ Y, int win0, int vbase, int Nout) {
    const int bx = blockIdx.x, by = blockIdx.y, z = blockIdx.z;
    const int tid = threadIdx.x, lane = tid & 63, wid = tid >> 6;
    const int wr = wid >> 1, wc = wid & 1;
    const int row0 = by * 128;
    const int win = win0 + z;
    __shared__ u16 lds[2][2][128 * 32];
    const u16* Az = (STAGE == 0) ? A : (A + (size_t)z * 2048 * 4096);
    const int skk = (lane & 3) * 8;

    auto stage = [&](int buf, int kt) {
        int k0 = kt * 32;
#pragma unroll
        for (int q = 0; q < 2; q++) {
            int r = wid * 32 + q * 16 + (lane >> 2);
            const u16* gs;
            if (STAGE == 0) {
                int kg = k0 + skk;
                gs = Az + (size_t)(row0 + r) * 12288 + (size_t)(win + (kg >> 10)) * 1024 + (kg & 1023);
            } else {
                gs = Az + (size_t)(row0 + r) * 4096 + k0 + skk;
            }
            GLL(gs, &lds[buf][0][(wid * 32 + q * 16) * 32]);
            int n = vbase + bx * 128 + r;
            GLL(Bt + (size_t)n * 4096 + k0 + skk, &lds[buf][1][(wid * 32 + q * 16) * 32]);
        }
    };

    f32x4 acc[4][4] = {};
    stage(0, 0);
    __syncthreads();
    const int a_off = (wr * 64 + (lane & 15)) * 32 + (lane >> 4) * 8;
    const int b_off = (wc * 64 + (lane & 15)) * 32 + (lane >> 4) * 8;
    for (int kt = 0; kt < 128; kt++) {
        int cur = kt & 1;
        if (kt < 127) stage(cur ^ 1, kt + 1);
        bf16x8 af[4], bq[4];
#pragma unroll
        for (int m = 0; m < 4; m++) af[m] = *(const bf16x8*)&lds[cur][0][a_off + m * 16 * 32];
#pragma unroll
        for (int n = 0; n < 4; n++) bq[n] = *(const bf16x8*)&lds[cur][1][b_off + n * 16 * 32];
#pragma unroll
        for (int m = 0; m < 4; m++)
#pragma unroll
            for (int n = 0; n < 4; n++)
                acc[m][n] = __builtin_amdgcn_mfma_f32_16x16x32_bf16(af[m], bq[n], acc[m][n], 0, 0, 0);
        __syncthreads();
    }
    u16* Yz = Y + (size_t)z * 2048 * Nout;
#pragma unroll
    for (int m = 0; m < 4; m++) {
        int row = row0 + wr * 64 + m * 16 + (lane >> 4) * 4;
#pragma unroll
        for (int n = 0; n < 4; n++) {
            int col = bx * 128 + wc * 64 + n * 16 + (lane & 15);
#pragma unroll
            for (int j = 0; j < 4; j++)
                Yz[(size_t)(row + j) * Nout + col] = f2b(acc[m][n][j]);
        }
    }
}

// ---------------------------------------------------------------------------
// GLU linear: P[(b,f)][v] = (Y_b^T W)[f][v] glu, K=64.
// grid (Nv/128, 32 b, nwin), block 256 (4 waves over v-quarters of 32)
// ---------------------------------------------------------------------------
__global__ __launch_bounds__(256) void glu_gemm(
    const u16* __restrict__ Y, const u16* __restrict__ Wt,
    const float* __restrict__ fcb, u16* __restrict__ P,
    int win0, int ks, int Nv) {
    const int bx = blockIdx.x, b = blockIdx.y, z = blockIdx.z;
    const int tid = threadIdx.x, lane = tid & 63, wid = tid >> 6;
    const int win = win0 + z;
    const int v0 = bx * 128;
    const u16* Yz = Y + ((size_t)z * 2048 + b * 64) * Nv;
    const u16* w = Wt + (size_t)(win * 3 + ks) * 128 * 64;
    const float* bias = fcb + (size_t)(win * 3 + ks) * 128;
    __shared__ u16 ylds[64 * 128];
#pragma unroll
    for (int q = 0; q < 4; q++) {
        int c = wid * 16 + q * 4 + (lane >> 4);
        GLL(Yz + (size_t)c * Nv + v0 + (lane & 15) * 8, &ylds[(wid * 16 + q * 4) * 128]);
    }
    __syncthreads();
    f32x4 acc[8][2] = {};
#pragma unroll
    for (int kf = 0; kf < 2; kf++) {
        bf16x8 bq[2];
#pragma unroll
        for (int n = 0; n < 2; n++) {
            int v = wid * 32 + n * 16 + (lane & 15);
            int cb = kf * 32 + (lane >> 4) * 8;
            short tv[8];
#pragma unroll
            for (int i = 0; i < 8; i++) tv[i] = (short)ylds[(cb + i) * 128 + v];
            bq[n] = (bf16x8){tv[0], tv[1], tv[2], tv[3], tv[4], tv[5], tv[6], tv[7]};
        }
#pragma unroll
        for (int m = 0; m < 8; m++) {
            bf16x8 af = *(const bf16x8*)&w[(m * 16 + (lane & 15)) * 64 + kf * 32 + (lane >> 4) * 8];
#pragma unroll
            for (int n = 0; n < 2; n++)
                acc[m][n] = __builtin_amdgcn_mfma_f32_16x16x32_bf16(af, bq[n], acc[m][n], 0, 0, 0);
        }
    }
    u16* Pz = P + ((size_t)z * 2048 + b * 64) * Nv;
#pragma unroll
    for (int m = 0; m < 4; m++) {
#pragma unroll
        for (int j = 0; j < 4; j++) {
            int f = m * 16 + (lane >> 4) * 4 + j;
            float b1 = bias[f], b2 = bias[f + 64];
#pragma unroll
            for (int n = 0; n < 2; n++) {
                float g1 = acc[m][n][j] + b1;
                float g2 = acc[m + 4][n][j] + b2;
                float val = g1 / (1.0f + expf(-g2));
                int v = v0 + wid * 32 + n * 16 + (lane & 15);
                Pz[(size_t)f * Nv + v] = f2b(val);
            }
        }
    }
}

// ---------------------------------------------------------------------------
// final: out[b,win,n,f] += max(P1mid, P2mid, P3)
// grid (16 ntiles, 32 b, nwin), block 256
// ---------------------------------------------------------------------------
__global__ void final_add(const u16* __restrict__ P1, const u16* __restrict__ P2,
                          const u16* __restrict__ P3, float* __restrict__ out, int win0) {
    const int n0 = blockIdx.x * 64, b = blockIdx.y, z = blockIdx.z;
    const int win = win0 + z;
    const int tid = threadIdx.x;
    __shared__ float tl[64][65];
    {
        int f = tid >> 2, q = tid & 3;
        size_t o12 = ((size_t)z * 2048 + b * 64 + f) * 4096 + 1024 + n0 + q * 16;
        size_t o3  = ((size_t)z * 2048 + b * 64 + f) * 1024 + n0 + q * 16;
#pragma unroll
        for (int i = 0; i < 16; i += 4) {
            uint2 a  = *(const uint2*)&P1[o12 + i];
            uint2 c2 = *(const uint2*)&P2[o12 + i];
            uint2 d  = *(const uint2*)&P3[o3 + i];
            u32 av[4] = {a.x & 0xffffu, a.x >> 16, a.y & 0xffffu, a.y >> 16};
            u32 bv[4] = {c2.x & 0xffffu, c2.x >> 16, c2.y & 0xffffu, c2.y >> 16};
            u32 dv[4] = {d.x & 0xffffu, d.x >> 16, d.y & 0xffffu, d.y >> 16};
#pragma unroll
            for (int jj = 0; jj < 4; jj++)
                tl[q * 16 + i + jj][f] = fmaxf(fmaxf(b2f(av[jj]), b2f(bv[jj])), b2f(dv[jj]));
        }
    }
    __syncthreads();
    {
        int n = tid >> 2, q = tid & 3;
        size_t oo = ((size_t)(b * 9 + win) * 1024 + n0 + n) * 64 + q * 16;
#pragma unroll
        for (int i = 0; i < 16; i += 4) {
            float4 cur = *(const float4*)&out[oo + i];
            cur.x += tl[n][q * 16 + i + 0];
            cur.y += tl[n][q * 16 + i + 1];
            cur.z += tl[n][q * 16 + i + 2];
            cur.w += tl[n][q * 16 + i + 3];
            *(float4*)&out[oo + i] = cur;
        }
    }
}

// ---------------------------------------------------------------------------
extern "C" void kernel_launch(void* const* d_in, const int* in_sizes, int n_in,
                              void* d_out, int out_size, void* d_ws, size_t ws_size,
                              hipStream_t stream) {
    const float* data = (const float*)d_in[0];
    const float* adj  = (const float*)d_in[1];
    const float* temb = (const float*)d_in[2];
    const float* semb = (const float*)d_in[3];
    const float* cwl  = (const float*)d_in[4];
    const float* cbl  = (const float*)d_in[5];
    const float* cwr  = (const float*)d_in[6];
    const float* cbr  = (const float*)d_in[7];
    const float* fcw  = (const float*)d_in[8];
    const float* fcb  = (const float*)d_in[9];
    float* out = (float*)d_out;

    char* p = (char*)d_ws;
    auto alloc = [&](size_t bytes) -> char* {
        char* r = p;
        p += (bytes + 255) & ~(size_t)255;
        return r;
    };
    const size_t SZ_XT  = 2048UL * 12288 * 2;
    const size_t SZ_XN  = 32UL * 12 * 1024 * 64 * 2;
    const size_t SZ_ADJ = 4096UL * 4096 * 2;
    const size_t SZ_WT  = 27UL * 128 * 64 * 2;
    const size_t SZ_WC  = 128UL * 128 * 2;
    u16* XT   = (u16*)alloc(SZ_XT);
    u16* Xn   = (u16*)alloc(SZ_XN);
    u16* adjb = (u16*)alloc(SZ_ADJ);
    u16* Wt   = (u16*)alloc(SZ_WT);
    u16* Wc   = (u16*)alloc(SZ_WC);
    size_t fixed = (size_t)(p - (char*)d_ws);
    const size_t perwin = 3UL * 16777216 + 4194304 + 4 * 256;
    int c = (fixed + 9 * perwin <= ws_size) ? 9 : (fixed + 3 * perwin <= ws_size) ? 3 : 1;
    u16* Ybuf = (u16*)alloc((size_t)c * 16777216);
    u16* P1   = (u16*)alloc((size_t)c * 16777216);
    u16* P2   = (u16*)alloc((size_t)c * 16777216);
    u16* P3   = (u16*)alloc((size_t)c * 4194304);

    cvt_f32_bf16<<<4096, 256, 0, stream>>>(adj, adjb, 4096 * 4096);
    prep_x<<<dim3(16, 12, 32), 256, 0, stream>>>(data, temb, semb, Xn, XT);
    prep_w<<<28, 256, 0, stream>>>(fcw, cwl, cwr, Wt, Wc);
    dconv_gemm<<<dim3(8, 9, 32), 256, 0, stream>>>(Xn, Wc, cbl, cbr, out);

    for (int w0 = 0; w0 < 9; w0 += c) {
        int cw = (9 - w0 < c) ? (9 - w0) : c;
        agg_gemm<0><<<dim3(32, 16, cw), 256, 0, stream>>>(XT, adjb, Ybuf, w0, 0, 4096);
        glu_gemm<<<dim3(32, 32, cw), 256, 0, stream>>>(Ybuf, Wt, fcb, P1, w0, 0, 4096);
        agg_gemm<1><<<dim3(32, 16, cw), 256, 0, stream>>>(P1, adjb, Ybuf, w0, 0, 4096);
        glu_gemm<<<dim3(32, 32, cw), 256, 0, stream>>>(Ybuf, Wt, fcb, P2, w0, 1, 4096);
        agg_gemm<1><<<dim3(8, 16, cw), 256, 0, stream>>>(P2, adjb, Ybuf, w0, 1024, 1024);
        glu_gemm<<<dim3(8, 32, cw), 256, 0, stream>>>(Ybuf, Wt, fcb, P3, w0, 2, 1024);
        final_add<<<dim3(16, 32, cw), 256, 0, stream>>>(P1, P2, P3, out, w0);
    }
}

// Round 2
// 1942.406 us; speedup vs baseline: 1.1865x; 1.1865x over previous
//
#include <hip/hip_runtime.h>
#include <math.h>

typedef unsigned short u16;
typedef unsigned int   u32;
typedef __attribute__((ext_vector_type(8))) short bf16x8;
typedef __attribute__((ext_vector_type(4))) float f32x4;

typedef const void __attribute__((address_space(1))) gv1_t;
typedef void       __attribute__((address_space(3))) lv3_t;
#define GLL(g, l) __builtin_amdgcn_global_load_lds((gv1_t*)(g), (lv3_t*)(l), 16, 0, 0)

__device__ __forceinline__ u16 f2b(float x) {
    union { float f; u32 u; } v; v.f = x;
    u32 r = v.u + 0x7FFFu + ((v.u >> 16) & 1u);
    return (u16)(r >> 16);
}
__device__ __forceinline__ float b2f(u32 x) {
    union { u32 u; float f; } v; v.u = x << 16;
    return v.f;
}

// ---------------------------------------------------------------------------
// prep: f32 -> bf16 convert (adj)
// ---------------------------------------------------------------------------
__global__ void cvt_f32_bf16(const float* __restrict__ a, u16* __restrict__ o, int n) {
    for (int i = (blockIdx.x * 256 + threadIdx.x) * 4; i < n; i += gridDim.x * 256 * 4) {
        float4 v = *(const float4*)&a[i];
        uint2 pk;
        pk.x = (u32)f2b(v.x) | ((u32)f2b(v.y) << 16);
        pk.y = (u32)f2b(v.z) | ((u32)f2b(v.w) << 16);
        *(uint2*)&o[i] = pk;
    }
}

// ---------------------------------------------------------------------------
// prep: x = data + temb + semb; write Xn [b][t][n][c] bf16 and XT [(b,c)][t*1024+n] bf16
// ---------------------------------------------------------------------------
__global__ void prep_x(const float* __restrict__ data, const float* __restrict__ temb,
                       const float* __restrict__ semb, u16* __restrict__ Xn, u16* __restrict__ XT) {
    const int n0 = blockIdx.x * 64, t = blockIdx.y, b = blockIdx.z;
    const int tid = threadIdx.x;
    __shared__ u16 lt[64][66];
#pragma unroll
    for (int p = 0; p < 4; p++) {
        int n = p * 16 + (tid >> 4);
        int c = (tid & 15) * 4;
        size_t gi = ((size_t)(b * 12 + t) * 1024 + n0 + n) * 64 + c;
        float4 v  = *(const float4*)&data[gi];
        float4 tv = *(const float4*)&temb[t * 64 + c];
        float4 sv = *(const float4*)&semb[(n0 + n) * 64 + c];
        u16 u0 = f2b(v.x + tv.x + sv.x);
        u16 u1 = f2b(v.y + tv.y + sv.y);
        u16 u2 = f2b(v.z + tv.z + sv.z);
        u16 u3 = f2b(v.w + tv.w + sv.w);
        uint2 pk; pk.x = (u32)u0 | ((u32)u1 << 16); pk.y = (u32)u2 | ((u32)u3 << 16);
        *(uint2*)&Xn[gi] = pk;
        lt[n][c + 0] = u0; lt[n][c + 1] = u1; lt[n][c + 2] = u2; lt[n][c + 3] = u3;
    }
    __syncthreads();
    const int c = tid >> 2, q = tid & 3;
    u16 u[16];
#pragma unroll
    for (int i = 0; i < 16; i++) u[i] = lt[q * 16 + i][c];
    size_t xo = ((size_t)(b * 64 + c)) * 12288 + (size_t)t * 1024 + n0 + q * 16;
    uint4 p0, p1;
    p0.x = (u32)u[0] | ((u32)u[1] << 16);  p0.y = (u32)u[2] | ((u32)u[3] << 16);
    p0.z = (u32)u[4] | ((u32)u[5] << 16);  p0.w = (u32)u[6] | ((u32)u[7] << 16);
    p1.x = (u32)u[8] | ((u32)u[9] << 16);  p1.y = (u32)u[10] | ((u32)u[11] << 16);
    p1.z = (u32)u[12] | ((u32)u[13] << 16); p1.w = (u32)u[14] | ((u32)u[15] << 16);
    *(uint4*)&XT[xo] = p0;
    *(uint4*)&XT[xo + 8] = p1;
}

// ---------------------------------------------------------------------------
// prep: fc_w [27][64][128] -> Wt [27][128][64] bf16 ; conv weights -> Wc [128][128] bf16
// ---------------------------------------------------------------------------
__global__ void prep_w(const float* __restrict__ fcw, const float* __restrict__ cwl,
                       const float* __restrict__ cwr, u16* __restrict__ Wt, u16* __restrict__ Wc) {
    const int blk = blockIdx.x, tid = threadIdx.x;
    if (blk < 27) {
        const float* src = fcw + (size_t)blk * 64 * 128;
        u16* dst = Wt + (size_t)blk * 128 * 64;
        for (int e = tid; e < 8192; e += 256) {
            int c = e >> 7, f = e & 127;
            dst[f * 64 + c] = f2b(src[c * 128 + f]);
        }
    } else {
        for (int e = tid; e < 16384; e += 256) {
            int o = e >> 7, k = e & 127;
            float v = (o < 64) ? cwl[(o * 64 + (k & 63)) * 2 + (k >> 6)]
                               : cwr[((o - 64) * 64 + (k & 63)) * 2 + (k >> 6)];
            Wc[o * 128 + k] = f2b(v);
        }
    }
}

// ---------------------------------------------------------------------------
// gated dilated conv as GEMM (unchanged)
// ---------------------------------------------------------------------------
__global__ __launch_bounds__(256) void dconv_gemm(
    const u16* __restrict__ Xn, const u16* __restrict__ Wc,
    const float* __restrict__ cbl, const float* __restrict__ cbr,
    float* __restrict__ out) {
    const int n0 = blockIdx.x * 128, t = blockIdx.y, b = blockIdx.z;
    const int tid = threadIdx.x, lane = tid & 63, wid = tid >> 6;
    __shared__ u16 alds[2][128 * 32];
    const u16* base0 = Xn + (size_t)(b * 12 + t) * 1024 * 64;
    const u16* base3 = Xn + (size_t)(b * 12 + t + 3) * 1024 * 64;

    auto stage = [&](int buf, int kt) {
        int k0 = kt * 32;
#pragma unroll
        for (int q = 0; q < 2; q++) {
            int r = wid * 32 + q * 16 + (lane >> 2);
            int k = k0 + (lane & 3) * 8;
            const u16* gs = (k < 64) ? base0 + (size_t)(n0 + r) * 64 + k
                                     : base3 + (size_t)(n0 + r) * 64 + (k - 64);
            GLL(gs, &alds[buf][(wid * 32 + q * 16) * 32]);
        }
    };

    f32x4 acc[2][8] = {};
    stage(0, 0);
    __syncthreads();
    const int a_off = (wid * 32 + (lane & 15)) * 32 + (lane >> 4) * 8;
    for (int kt = 0; kt < 4; kt++) {
        int cur = kt & 1;
        if (kt < 3) stage(cur ^ 1, kt + 1);
        bf16x8 af[2];
#pragma unroll
        for (int m = 0; m < 2; m++) af[m] = *(const bf16x8*)&alds[cur][a_off + m * 16 * 32];
#pragma unroll
        for (int n = 0; n < 8; n++) {
            bf16x8 bq = *(const bf16x8*)&Wc[(n * 16 + (lane & 15)) * 128 + kt * 32 + (lane >> 4) * 8];
#pragma unroll
            for (int m = 0; m < 2; m++)
                acc[m][n] = __builtin_amdgcn_mfma_f32_16x16x32_bf16(af[m], bq, acc[m][n], 0, 0, 0);
        }
        __syncthreads();
    }
#pragma unroll
    for (int m = 0; m < 2; m++) {
#pragma unroll
        for (int n = 0; n < 4; n++) {
            int fp = n * 16 + (lane & 15);
            float b1 = cbl[fp], b2 = cbr[fp];
#pragma unroll
            for (int j = 0; j < 4; j++) {
                int row = wid * 32 + m * 16 + (lane >> 4) * 4 + j;
                float gl = acc[m][n][j] + b1;
                float gr = acc[m][n + 4][j] + b2;
                out[((size_t)(b * 9 + t) * 1024 + n0 + row) * 64 + fp] =
                    (1.0f / (1.0f + expf(-gl))) * tanhf(gr);
            }
        }
    }
}

// ---------------------------------------------------------------------------
// 8-phase 256x256 agg GEMM (T2 swizzle + T3/T4 counted vmcnt + T5 setprio).
// Y[(b,c)][v] = sum_w A[(b,c)][w] * adj[v][w]; M=2048/window, N=4096, K=4096.
// 512 threads = 8 waves (2 Mx4 N), BK=64, LDS 128KB double-buffered.
// LDS layout: [buf][A/B][half(128 rows)][128x64 u16], row-major with
// XOR swizzle: LDS[r][hw] holds global (r, hw ^ ((r&7)<<3)). global_load_lds
// writes linearly (lane*16B); source address carries the inverse swizzle.
// ---------------------------------------------------------------------------
#define SB() do { __builtin_amdgcn_sched_barrier(0); __builtin_amdgcn_s_barrier(); __builtin_amdgcn_sched_barrier(0); } while (0)
#define GATE() asm volatile("s_waitcnt vmcnt(4)" ::: "memory")

template <int STAGE>
__global__ __launch_bounds__(512, 2) void agg_gemm8(
    const u16* __restrict__ A, const u16* __restrict__ Bt,
    u16* __restrict__ Y, int win0) {
    const int bx = blockIdx.x, by = blockIdx.y, z = blockIdx.z;
    const int tid = threadIdx.x, lane = tid & 63, wid = tid >> 6;
    const int wr = wid >> 2, wc = wid & 3;
    const int rowBase = by * 256, colBase = bx * 256;
    const int win = win0 + z;
    __shared__ u16 lds[2][2][2][128 * 64];  // 128 KiB
    const u16* Az = (STAGE == 0) ? A : (A + (size_t)z * 2048 * 4096);

    const int srow = lane >> 3;                 // row within 8-row stripe
    const int skb  = 8 * ((lane & 7) ^ srow);   // inverse-swizzled k halfword

    // one statement stages 8 waves x 8 rows x 64 hw = 64 rows; s in {0,1}
    auto stageA = [&](int buf, int half, int s, int kt) {
        kt &= 63;
        int r0 = s * 64 + wid * 8;
        int row_g = rowBase + half * 128 + r0 + srow;
        const u16* src;
        if (STAGE == 0) {
            int k = kt * 64 + skb;
            src = Az + (size_t)row_g * 12288 + (size_t)(win + (k >> 10)) * 1024 + (k & 1023);
        } else {
            src = Az + (size_t)row_g * 4096 + kt * 64 + skb;
        }
        GLL(src, &lds[buf][0][half][r0 * 64]);
    };
    auto stageB = [&](int buf, int half, int s, int kt) {
        kt &= 63;
        int r0 = s * 64 + wid * 8;
        int col_g = colBase + half * 128 + r0 + srow;
        GLL(Bt + (size_t)col_g * 4096 + kt * 64 + skb, &lds[buf][1][half][r0 * 64]);
    };
#define STH_A(buf, half, kt) do { stageA(buf, half, 0, kt); stageA(buf, half, 1, kt); } while (0)
#define STH_B(buf, half, kt) do { stageB(buf, half, 0, kt); stageB(buf, half, 1, kt); } while (0)

    f32x4 acc[8][4] = {};
    bf16x8 aF[4][2], bF[4][2];

#define READ_A(buf, mb)                                                       \
    _Pragma("unroll") for (int mm = 0; mm < 4; mm++)                          \
    _Pragma("unroll") for (int kk = 0; kk < 2; kk++) {                        \
        int r = ((mb) + mm) * 16 + (lane & 15);                               \
        int hw = (kk * 32 + (lane >> 4) * 8) ^ ((r & 7) << 3);                \
        aF[mm][kk] = *(const bf16x8*)&lds[buf][0][wr][r * 64 + hw];           \
    }
#define READ_B(buf, nb)                                                       \
    _Pragma("unroll") for (int nn = 0; nn < 2; nn++)                          \
    _Pragma("unroll") for (int kk = 0; kk < 2; kk++) {                        \
        int r = (wc & 1) * 64 + ((nb) + nn) * 16 + (lane & 15);               \
        int hw = (kk * 32 + (lane >> 4) * 8) ^ ((r & 7) << 3);                \
        bF[(nb) + nn][kk] = *(const bf16x8*)&lds[buf][1][wc >> 1][r * 64 + hw]; \
    }
#define MFMA8(mb, nb)                                                         \
    __builtin_amdgcn_s_setprio(1);                                            \
    _Pragma("unroll") for (int mm = 0; mm < 4; mm++)                          \
    _Pragma("unroll") for (int nn = 0; nn < 2; nn++)                          \
    _Pragma("unroll") for (int kk = 0; kk < 2; kk++)                          \
        acc[(mb) + mm][(nb) + nn] = __builtin_amdgcn_mfma_f32_16x16x32_bf16(  \
            aF[mm][kk], bF[(nb) + nn][kk], acc[(mb) + mm][(nb) + nn], 0, 0, 0); \
    __builtin_amdgcn_s_setprio(0);

    // prologue: tile0 -> buf0 (B0,A0,B1,A1); tile1 -> buf1 (B0,A0)
    STH_B(0, 0, 0); STH_A(0, 0, 0); STH_B(0, 1, 0); STH_A(0, 1, 0);
    STH_B(1, 0, 1); STH_A(1, 0, 1);
    GATE();  // tile0 fully landed; tile1 B0/A0 still in flight
    SB();

    for (int i = 0; i < 32; i++) {
        int t1 = 2 * i + 1, t2 = 2 * i + 2, t3 = 2 * i + 3;
        // ---- K-tile 2i in buf0 ----
        READ_A(0, 0); READ_B(0, 0);
        STH_B(1, 1, t1);
        SB(); MFMA8(0, 0); SB();

        READ_B(0, 2);
        STH_A(1, 1, t1);
        SB(); MFMA8(0, 2); SB();

        READ_A(0, 4);
        STH_B(0, 0, t2);
        SB(); MFMA8(4, 0); SB();

        STH_A(0, 0, t2);
        SB(); MFMA8(4, 2); GATE(); SB();   // tile 2i+1 fully landed

        // ---- K-tile 2i+1 in buf1 ----
        READ_A(1, 0); READ_B(1, 0);
        STH_B(0, 1, t2);
        SB(); MFMA8(0, 0); SB();

        READ_B(1, 2);
        STH_A(0, 1, t2);
        SB(); MFMA8(0, 2); SB();

        READ_A(1, 4);
        STH_B(1, 0, t3);
        SB(); MFMA8(4, 0); SB();

        STH_A(1, 0, t3);
        SB(); MFMA8(4, 2); GATE(); SB();   // tile 2i+2 fully landed
    }

    u16* Yz = Y + (size_t)z * 2048 * 4096;
#pragma unroll
    for (int m = 0; m < 8; m++) {
        int row = rowBase + wr * 128 + m * 16 + (lane >> 4) * 4;
#pragma unroll
        for (int n = 0; n < 4; n++) {
            int col = colBase + wc * 64 + n * 16 + (lane & 15);
#pragma unroll
            for (int j = 0; j < 4; j++)
                Yz[(size_t)(row + j) * 4096 + col] = f2b(acc[m][n][j]);
        }
    }
#undef READ_A
#undef READ_B
#undef MFMA8
#undef STH_A
#undef STH_B
}

// ---------------------------------------------------------------------------
// 128x128 2-phase agg GEMM — kept for the small layer-3 aggregation (N=1024)
// ---------------------------------------------------------------------------
template <int STAGE>
__global__ __launch_bounds__(256) void agg_gemm(
    const u16* __restrict__ A, const u16* __restrict__ Bt,
    u16* __restrict__ Y, int win0, int vbase, int Nout) {
    const int bx = blockIdx.x, by = blockIdx.y, z = blockIdx.z;
    const int tid = threadIdx.x, lane = tid & 63, wid = tid >> 6;
    const int wr = wid >> 1, wc = wid & 1;
    const int row0 = by * 128;
    const int win = win0 + z;
    __shared__ u16 lds[2][2][128 * 32];
    const u16* Az = (STAGE == 0) ? A : (A + (size_t)z * 2048 * 4096);
    const int skk = (lane & 3) * 8;

    auto stage = [&](int buf, int kt) {
        int k0 = kt * 32;
#pragma unroll
        for (int q = 0; q < 2; q++) {
            int r = wid * 32 + q * 16 + (lane >> 2);
            const u16* gs;
            if (STAGE == 0) {
                int kg = k0 + skk;
                gs = Az + (size_t)(row0 + r) * 12288 + (size_t)(win + (kg >> 10)) * 1024 + (kg & 1023);
            } else {
                gs = Az + (size_t)(row0 + r) * 4096 + k0 + skk;
            }
            GLL(gs, &lds[buf][0][(wid * 32 + q * 16) * 32]);
            int n = vbase + bx * 128 + r;
            GLL(Bt + (size_t)n * 4096 + k0 + skk, &lds[buf][1][(wid * 32 + q * 16) * 32]);
        }
    };

    f32x4 acc[4][4] = {};
    stage(0, 0);
    __syncthreads();
    const int a_off = (wr * 64 + (lane & 15)) * 32 + (lane >> 4) * 8;
    const int b_off = (wc * 64 + (lane & 15)) * 32 + (lane >> 4) * 8;
    for (int kt = 0; kt < 128; kt++) {
        int cur = kt & 1;
        if (kt < 127) stage(cur ^ 1, kt + 1);
        bf16x8 af[4], bq[4];
#pragma unroll
        for (int m = 0; m < 4; m++) af[m] = *(const bf16x8*)&lds[cur][0][a_off + m * 16 * 32];
#pragma unroll
        for (int n = 0; n < 4; n++) bq[n] = *(const bf16x8*)&lds[cur][1][b_off + n * 16 * 32];
#pragma unroll
        for (int m = 0; m < 4; m++)
#pragma unroll
            for (int n = 0; n < 4; n++)
                acc[m][n] = __builtin_amdgcn_mfma_f32_16x16x32_bf16(af[m], bq[n], acc[m][n], 0, 0, 0);
        __syncthreads();
    }
    u16* Yz = Y + (size_t)z * 2048 * Nout;
#pragma unroll
    for (int m = 0; m < 4; m++) {
        int row = row0 + wr * 64 + m * 16 + (lane >> 4) * 4;
#pragma unroll
        for (int n = 0; n < 4; n++) {
            int col = bx * 128 + wc * 64 + n * 16 + (lane & 15);
#pragma unroll
            for (int j = 0; j < 4; j++)
                Yz[(size_t)(row + j) * Nout + col] = f2b(acc[m][n][j]);
        }
    }
}

// ---------------------------------------------------------------------------
// GLU linear (unchanged)
// ---------------------------------------------------------------------------
__global__ __launch_bounds__(256) void glu_gemm(
    const u16* __restrict__ Y, const u16* __restrict__ Wt,
    const float* __restrict__ fcb, u16* __restrict__ P,
    int win0, int ks, int Nv) {
    const int bx = blockIdx.x, b = blockIdx.y, z = blockIdx.z;
    const int tid = threadIdx.x, lane = tid & 63, wid = tid >> 6;
    const int win = win0 + z;
    const int v0 = bx * 128;
    const u16* Yz = Y + ((size_t)z * 2048 + b * 64) * Nv;
    const u16* w = Wt + (size_t)(win * 3 + ks) * 128 * 64;
    const float* bias = fcb + (size_t)(win * 3 + ks) * 128;
    __shared__ u16 ylds[64 * 128];
#pragma unroll
    for (int q = 0; q < 4; q++) {
        int c = wid * 16 + q * 4 + (lane >> 4);
        GLL(Yz + (size_t)c * Nv + v0 + (lane & 15) * 8, &ylds[(wid * 16 + q * 4) * 128]);
    }
    __syncthreads();
    f32x4 acc[8][2] = {};
#pragma unroll
    for (int kf = 0; kf < 2; kf++) {
        bf16x8 bq[2];
#pragma unroll
        for (int n = 0; n < 2; n++) {
            int v = wid * 32 + n * 16 + (lane & 15);
            int cb = kf * 32 + (lane >> 4) * 8;
            short tv[8];
#pragma unroll
            for (int i = 0; i < 8; i++) tv[i] = (short)ylds[(cb + i) * 128 + v];
            bq[n] = (bf16x8){tv[0], tv[1], tv[2], tv[3], tv[4], tv[5], tv[6], tv[7]};
        }
#pragma unroll
        for (int m = 0; m < 8; m++) {
            bf16x8 af = *(const bf16x8*)&w[(m * 16 + (lane & 15)) * 64 + kf * 32 + (lane >> 4) * 8];
#pragma unroll
            for (int n = 0; n < 2; n++)
                acc[m][n] = __builtin_amdgcn_mfma_f32_16x16x32_bf16(af, bq[n], acc[m][n], 0, 0, 0);
        }
    }
    u16* Pz = P + ((size_t)z * 2048 + b * 64) * Nv;
#pragma unroll
    for (int m = 0; m < 4; m++) {
#pragma unroll
        for (int j = 0; j < 4; j++) {
            int f = m * 16 + (lane >> 4) * 4 + j;
            float b1 = bias[f], b2 = bias[f + 64];
#pragma unroll
            for (int n = 0; n < 2; n++) {
                float g1 = acc[m][n][j] + b1;
                float g2 = acc[m + 4][n][j] + b2;
                float val = g1 / (1.0f + expf(-g2));
                int v = v0 + wid * 32 + n * 16 + (lane & 15);
                Pz[(size_t)f * Nv + v] = f2b(val);
            }
        }
    }
}

// ---------------------------------------------------------------------------
// final: out[b,win,n,f] += max(P1mid, P2mid, P3) (unchanged)
// ---------------------------------------------------------------------------
__global__ void final_add(const u16* __restrict__ P1, const u16* __restrict__ P2,
                          const u16* __restrict__ P3, float* __restrict__ out, int win0) {
    const int n0 = blockIdx.x * 64, b = blockIdx.y, z = blockIdx.z;
    const int win = win0 + z;
    const int tid = threadIdx.x;
    __shared__ float tl[64][65];
    {
        int f = tid >> 2, q = tid & 3;
        size_t o12 = ((size_t)z * 2048 + b * 64 + f) * 4096 + 1024 + n0 + q * 16;
        size_t o3  = ((size_t)z * 2048 + b * 64 + f) * 1024 + n0 + q * 16;
#pragma unroll
        for (int i = 0; i < 16; i += 4) {
            uint2 a  = *(const uint2*)&P1[o12 + i];
            uint2 c2 = *(const uint2*)&P2[o12 + i];
            uint2 d  = *(const uint2*)&P3[o3 + i];
            u32 av[4] = {a.x & 0xffffu, a.x >> 16, a.y & 0xffffu, a.y >> 16};
            u32 bv[4] = {c2.x & 0xffffu, c2.x >> 16, c2.y & 0xffffu, c2.y >> 16};
            u32 dv[4] = {d.x & 0xffffu, d.x >> 16, d.y & 0xffffu, d.y >> 16};
#pragma unroll
            for (int jj = 0; jj < 4; jj++)
                tl[q * 16 + i + jj][f] = fmaxf(fmaxf(b2f(av[jj]), b2f(bv[jj])), b2f(dv[jj]));
        }
    }
    __syncthreads();
    {
        int n = tid >> 2, q = tid & 3;
        size_t oo = ((size_t)(b * 9 + win) * 1024 + n0 + n) * 64 + q * 16;
#pragma unroll
        for (int i = 0; i < 16; i += 4) {
            float4 cur = *(const float4*)&out[oo + i];
            cur.x += tl[n][q * 16 + i + 0];
            cur.y += tl[n][q * 16 + i + 1];
            cur.z += tl[n][q * 16 + i + 2];
            cur.w += tl[n][q * 16 + i + 3];
            *(float4*)&out[oo + i] = cur;
        }
    }
}

// ---------------------------------------------------------------------------
extern "C" void kernel_launch(void* const* d_in, const int* in_sizes, int n_in,
                              void* d_out, int out_size, void* d_ws, size_t ws_size,
                              hipStream_t stream) {
    const float* data = (const float*)d_in[0];
    const float* adj  = (const float*)d_in[1];
    const float* temb = (const float*)d_in[2];
    const float* semb = (const float*)d_in[3];
    const float* cwl  = (const float*)d_in[4];
    const float* cbl  = (const float*)d_in[5];
    const float* cwr  = (const float*)d_in[6];
    const float* cbr  = (const float*)d_in[7];
    const float* fcw  = (const float*)d_in[8];
    const float* fcb  = (const float*)d_in[9];
    float* out = (float*)d_out;

    char* p = (char*)d_ws;
    auto alloc = [&](size_t bytes) -> char* {
        char* r = p;
        p += (bytes + 255) & ~(size_t)255;
        return r;
    };
    const size_t SZ_XT  = 2048UL * 12288 * 2;
    const size_t SZ_XN  = 32UL * 12 * 1024 * 64 * 2;
    const size_t SZ_ADJ = 4096UL * 4096 * 2;
    const size_t SZ_WT  = 27UL * 128 * 64 * 2;
    const size_t SZ_WC  = 128UL * 128 * 2;
    u16* XT   = (u16*)alloc(SZ_XT);
    u16* Xn   = (u16*)alloc(SZ_XN);
    u16* adjb = (u16*)alloc(SZ_ADJ);
    u16* Wt   = (u16*)alloc(SZ_WT);
    u16* Wc   = (u16*)alloc(SZ_WC);
    size_t fixed = (size_t)(p - (char*)d_ws);
    const size_t perwin = 3UL * 16777216 + 4194304 + 4 * 256;
    int c = (fixed + 9 * perwin <= ws_size) ? 9 : (fixed + 3 * perwin <= ws_size) ? 3 : 1;
    u16* Ybuf = (u16*)alloc((size_t)c * 16777216);
    u16* P1   = (u16*)alloc((size_t)c * 16777216);
    u16* P2   = (u16*)alloc((size_t)c * 16777216);
    u16* P3   = (u16*)alloc((size_t)c * 4194304);

    cvt_f32_bf16<<<4096, 256, 0, stream>>>(adj, adjb, 4096 * 4096);
    prep_x<<<dim3(16, 12, 32), 256, 0, stream>>>(data, temb, semb, Xn, XT);
    prep_w<<<28, 256, 0, stream>>>(fcw, cwl, cwr, Wt, Wc);
    dconv_gemm<<<dim3(8, 9, 32), 256, 0, stream>>>(Xn, Wc, cbl, cbr, out);

    for (int w0 = 0; w0 < 9; w0 += c) {
        int cw = (9 - w0 < c) ? (9 - w0) : c;
        agg_gemm8<0><<<dim3(16, 8, cw), 512, 0, stream>>>(XT, adjb, Ybuf, w0);
        glu_gemm<<<dim3(32, 32, cw), 256, 0, stream>>>(Ybuf, Wt, fcb, P1, w0, 0, 4096);
        agg_gemm8<1><<<dim3(16, 8, cw), 512, 0, stream>>>(P1, adjb, Ybuf, w0);
        glu_gemm<<<dim3(32, 32, cw), 256, 0, stream>>>(Ybuf, Wt, fcb, P2, w0, 1, 4096);
        agg_gemm<1><<<dim3(8, 16, cw), 256, 0, stream>>>(P2, adjb, Ybuf, w0, 1024, 1024);
        glu_gemm<<<dim3(8, 32, cw), 256, 0, stream>>>(Ybuf, Wt, fcb, P3, w0, 2, 1024);
        final_add<<<dim3(16, 32, cw), 256, 0, stream>>>(P1, P2, P3, out, w0);
    }
}